// Round 5
// baseline (378.559 us; speedup 1.0000x reference)
//
#include <hip/hip_runtime.h>
#include <hip/hip_bf16.h>
#include <math.h>

constexpr int kB = 16;
constexpr int kN = 1024;
constexpr int kD = 128;
constexpr int kE = 16384;

typedef short bf16x8 __attribute__((ext_vector_type(8)));
typedef float f32x4 __attribute__((ext_vector_type(4)));
typedef unsigned short us4 __attribute__((ext_vector_type(4)));

__device__ __forceinline__ float selu_f(float x) {
    const float scale = 1.0507009873554805f;
    const float alpha = 1.6732632423543772f;
    return x > 0.f ? scale * x : scale * alpha * (expf(x) - 1.f);
}

__device__ __forceinline__ float sigmoid_f(float x) {
    return 1.f / (1.f + expf(-x));
}

__device__ __forceinline__ float bf2f(unsigned short u) {
    union { unsigned int i; float f; } x;
    x.i = ((unsigned int)u) << 16;
    return x.f;
}

// round-to-nearest-even f32 -> bf16 (finite values; matches __float2bfloat16)
__device__ __forceinline__ unsigned short f2bf(float f) {
    union { float f; unsigned int i; } u;
    u.f = f;
    const unsigned int r = u.i + 0x7fffu + ((u.i >> 16) & 1u);
    return (unsigned short)(r >> 16);
}

// ---------- fused sort-by-target: count + scan + scatter (single block) ----------
__global__ void k_sort(const int* __restrict__ src, const int* __restrict__ tgt,
                       int* __restrict__ rowstart, int* __restrict__ sid,
                       int* __restrict__ ssrc) {
    __shared__ int cnt[kN];
    __shared__ int sc[kN];
    const int t = threadIdx.x;  // 1024
    cnt[t] = 0;
    __syncthreads();
    for (int e = t; e < kE; e += 1024) atomicAdd(&cnt[tgt[e]], 1);
    __syncthreads();
    const int own = cnt[t];
    sc[t] = own;
    __syncthreads();
    for (int off = 1; off < kN; off <<= 1) {
        int add = (t >= off) ? sc[t - off] : 0;
        __syncthreads();
        sc[t] += add;
        __syncthreads();
    }
    const int excl = sc[t] - own;
    rowstart[t] = excl;
    if (t == kN - 1) rowstart[kN] = sc[t];
    cnt[t] = excl;  // becomes cursor
    __syncthreads();
    for (int e = t; e < kE; e += 1024) {
        const int tg = tgt[e];
        const int pos = atomicAdd(&cnt[tg], 1);
        sid[pos] = e;
        ssrc[pos] = src[e];
    }
}

__global__ void k_gather_ef(const float* __restrict__ edgef, const int* __restrict__ src,
                            const int* __restrict__ tgt, const int* __restrict__ sid,
                            float* __restrict__ efg) {
    int gid = blockIdx.x * 256 + threadIdx.x;  // < kB*kE
    int b = gid >> 14;
    int i = gid & (kE - 1);
    int eid = sid[i];
    efg[gid] = edgef[(size_t)b * kN * kN + (size_t)src[eid] * kN + tgt[eid]];
}

// h init: fp32 copy + bf16 shadow
__global__ void k_h0(const float* __restrict__ nodef, float* __restrict__ h,
                     unsigned short* __restrict__ h_bf) {
    int gid = blockIdx.x * 256 + threadIdx.x;
    float v = nodef[gid];
    h[gid] = v;
    h_bf[gid] = f2bf(v);
}

// WcatT[j][k] (640 x 128 bf16), j<128: W1^T, j<256: W2^T, j>=256: Whh raw rows.
// WihB[j][k] (384 x 128 bf16) = Wih raw rows.
__global__ void k_buildw(const float* __restrict__ Wmsg, const float* __restrict__ Whh,
                         const float* __restrict__ Wih,
                         unsigned short* __restrict__ WcatT, unsigned short* __restrict__ WihB) {
    int j = blockIdx.x;   // 640
    int k = threadIdx.x;  // 128
    float v;
    if (j < 128)      v = Wmsg[k * 128 + j];
    else if (j < 256) v = Wmsg[(128 + k) * 128 + (j - 128)];
    else              v = Whh[(size_t)(j - 256) * 128 + k];
    WcatT[j * 128 + k] = f2bf(v);
    if (j < 384) WihB[j * 128 + k] = f2bf(Wih[(size_t)j * 128 + k]);
}

// ---------- MFMA GEMM (h @ Wcat): cols<256 -> HST bf16 (no bias), cols>=256 -> gh fp32 (+bhh)
// Block 256 (4 waves), C-tile 128x128, K=128 single-shot, XOR-swizzled LDS.
__launch_bounds__(256)
__global__ void k_mm640(const unsigned short* __restrict__ A,
                        const unsigned short* __restrict__ Bt,
                        const float* __restrict__ bhh,
                        unsigned short* __restrict__ HST, float* __restrict__ gh) {
    __shared__ uint4 As[2048];
    __shared__ uint4 Bs[2048];
    const int t = threadIdx.x;
    const int r0 = blockIdx.x * 128;
    const int c0 = blockIdx.y * 128;
    const uint4* gA = (const uint4*)(A + (size_t)r0 * 128);
    const uint4* gB = (const uint4*)(Bt + (size_t)c0 * 128);
#pragma unroll
    for (int i = 0; i < 8; ++i) {
        const int f = i * 256 + t;
        const int row = f >> 4, c16 = f & 15;
        const int d = row * 16 + (c16 ^ (row & 7));
        As[d] = gA[f];
        Bs[d] = gB[f];
    }
    __syncthreads();
    const int w = t >> 6, l = t & 63;
    const int wm = (w & 1) * 64, wn = (w >> 1) * 64;
    const int lin = l & 15, kq = l >> 4;
    f32x4 acc[4][4] = {};
#pragma unroll
    for (int s = 0; s < 4; ++s) {
        bf16x8 a[4], b[4];
#pragma unroll
        for (int mi = 0; mi < 4; ++mi) {
            const int row = wm + mi * 16 + lin;
            a[mi] = *(const bf16x8*)&As[row * 16 + ((s * 4 + kq) ^ (row & 7))];
        }
#pragma unroll
        for (int ni = 0; ni < 4; ++ni) {
            const int row = wn + ni * 16 + lin;
            b[ni] = *(const bf16x8*)&Bs[row * 16 + ((s * 4 + kq) ^ (row & 7))];
        }
#pragma unroll
        for (int mi = 0; mi < 4; ++mi)
#pragma unroll
            for (int ni = 0; ni < 4; ++ni)
                acc[mi][ni] = __builtin_amdgcn_mfma_f32_16x16x32_bf16(
                    a[mi], b[ni], acc[mi][ni], 0, 0, 0);
    }
    const int rq = kq * 4;
    if (c0 < 256) {
#pragma unroll
        for (int ni = 0; ni < 4; ++ni) {
            const int col = c0 + wn + ni * 16 + lin;
#pragma unroll
            for (int mi = 0; mi < 4; ++mi) {
                const int row = r0 + wm + mi * 16 + rq;
#pragma unroll
                for (int r = 0; r < 4; ++r)
                    HST[(size_t)(row + r) * 256 + col] = f2bf(acc[mi][ni][r]);
            }
        }
    } else {
#pragma unroll
        for (int ni = 0; ni < 4; ++ni) {
            const int gcol = (c0 - 256) + wn + ni * 16 + lin;
            const float bv = bhh[gcol];
#pragma unroll
            for (int mi = 0; mi < 4; ++mi) {
                const int row = r0 + wm + mi * 16 + rq;
#pragma unroll
                for (int r = 0; r < 4; ++r)
                    gh[(size_t)(row + r) * 384 + gcol] = acc[mi][ni][r] + bv;
            }
        }
    }
}

// ---------- MFMA GEMM: gi = agg_bf @ WihB^T + bih (fp32 out) ----------
__launch_bounds__(256)
__global__ void k_mm384(const unsigned short* __restrict__ A,
                        const unsigned short* __restrict__ Bt,
                        const float* __restrict__ bias, float* __restrict__ C) {
    __shared__ uint4 As[2048];
    __shared__ uint4 Bs[2048];
    const int t = threadIdx.x;
    const int r0 = blockIdx.x * 128;
    const int c0 = blockIdx.y * 128;
    const uint4* gA = (const uint4*)(A + (size_t)r0 * 128);
    const uint4* gB = (const uint4*)(Bt + (size_t)c0 * 128);
#pragma unroll
    for (int i = 0; i < 8; ++i) {
        const int f = i * 256 + t;
        const int row = f >> 4, c16 = f & 15;
        const int d = row * 16 + (c16 ^ (row & 7));
        As[d] = gA[f];
        Bs[d] = gB[f];
    }
    __syncthreads();
    const int w = t >> 6, l = t & 63;
    const int wm = (w & 1) * 64, wn = (w >> 1) * 64;
    const int lin = l & 15, kq = l >> 4;
    f32x4 acc[4][4] = {};
#pragma unroll
    for (int s = 0; s < 4; ++s) {
        bf16x8 a[4], b[4];
#pragma unroll
        for (int mi = 0; mi < 4; ++mi) {
            const int row = wm + mi * 16 + lin;
            a[mi] = *(const bf16x8*)&As[row * 16 + ((s * 4 + kq) ^ (row & 7))];
        }
#pragma unroll
        for (int ni = 0; ni < 4; ++ni) {
            const int row = wn + ni * 16 + lin;
            b[ni] = *(const bf16x8*)&Bs[row * 16 + ((s * 4 + kq) ^ (row & 7))];
        }
#pragma unroll
        for (int mi = 0; mi < 4; ++mi)
#pragma unroll
            for (int ni = 0; ni < 4; ++ni)
                acc[mi][ni] = __builtin_amdgcn_mfma_f32_16x16x32_bf16(
                    a[mi], b[ni], acc[mi][ni], 0, 0, 0);
    }
    const int rq = kq * 4;
#pragma unroll
    for (int ni = 0; ni < 4; ++ni) {
        const int col = c0 + wn + ni * 16 + lin;
        const float bv = bias[col];
#pragma unroll
        for (int mi = 0; mi < 4; ++mi) {
            const int row = r0 + wm + mi * 16 + rq;
#pragma unroll
            for (int r = 0; r < 4; ++r)
                C[(size_t)(row + r) * 384 + col] = acc[mi][ni][r] + bv;
        }
    }
}

// ---------- per-target edge reduce: 8 targets/block, 32 lanes x 4 cols each ----------
__launch_bounds__(256)
__global__ void k_edge(const unsigned short* __restrict__ HST, const float* __restrict__ efg,
                       const int* __restrict__ ssrc, const int* __restrict__ rowstart,
                       const float* __restrict__ Wmsg, const float* __restrict__ bmsg,
                       unsigned short* __restrict__ agg_bf) {
    const int t = threadIdx.x;
    const int b = blockIdx.y;
    const int tg = blockIdx.x * 8 + (t >> 5);
    const int c = (t & 31) * 4;
    const float4 w3 = *(const float4*)&Wmsg[256 * 128 + c];
    const float4 bm = *(const float4*)&bmsg[c];
    const size_t base = (size_t)b * kN;
    const us4 htu = *(const us4*)&HST[(base + tg) * 256 + 128 + c];
    const float hb0 = bf2f(htu.x) + bm.x;
    const float hb1 = bf2f(htu.y) + bm.y;
    const float hb2 = bf2f(htu.z) + bm.z;
    const float hb3 = bf2f(htu.w) + bm.w;
    const float* efb = efg + b * kE;
    const int j0 = rowstart[tg], j1 = rowstart[tg + 1];
    float a0 = 0.f, a1 = 0.f, a2 = 0.f, a3 = 0.f;
    int j = j0;
    us4 hsn = {};
    float efn = 0.f;
    if (j < j1) {
        const int s = ssrc[j];
        efn = efb[j];
        hsn = *(const us4*)&HST[(base + s) * 256 + c];
    }
    while (j < j1) {
        const us4 hs = hsn;
        const float ef = efn;
        const int jn = j + 1;
        if (jn < j1) {
            const int s2 = ssrc[jn];
            efn = efb[jn];
            hsn = *(const us4*)&HST[(base + s2) * 256 + c];
        }
        a0 += selu_f(bf2f(hs.x) + fmaf(ef, w3.x, hb0));
        a1 += selu_f(bf2f(hs.y) + fmaf(ef, w3.y, hb1));
        a2 += selu_f(bf2f(hs.z) + fmaf(ef, w3.z, hb2));
        a3 += selu_f(bf2f(hs.w) + fmaf(ef, w3.w, hb3));
        j = jn;
    }
    us4 o;
    o.x = f2bf(a0);
    o.y = f2bf(a1);
    o.z = f2bf(a2);
    o.w = f2bf(a3);
    *(us4*)&agg_bf[(base + tg) * 128 + c] = o;
}

// ---------- elementwise GRU, float4 ----------
__global__ void k_gru(const float* __restrict__ gi, const float* __restrict__ gh,
                      float* __restrict__ h, unsigned short* __restrict__ h_bf) {
    const int gid = blockIdx.x * 256 + threadIdx.x;  // < kB*kN*kD/4
    const int row = gid >> 5, q = (gid & 31) * 4;
    const float* gir = gi + (size_t)row * 384;
    const float* ghr = gh + (size_t)row * 384;
    const float4 ir = *(const float4*)&gir[q];
    const float4 iz = *(const float4*)&gir[q + 128];
    const float4 in = *(const float4*)&gir[q + 256];
    const float4 hr = *(const float4*)&ghr[q];
    const float4 hz = *(const float4*)&ghr[q + 128];
    const float4 hn = *(const float4*)&ghr[q + 256];
    float4 hv = *(const float4*)&h[(size_t)row * 128 + q];
    float o[4];
    const float irr[4] = {ir.x, ir.y, ir.z, ir.w};
    const float izz[4] = {iz.x, iz.y, iz.z, iz.w};
    const float inn[4] = {in.x, in.y, in.z, in.w};
    const float hrr[4] = {hr.x, hr.y, hr.z, hr.w};
    const float hzz[4] = {hz.x, hz.y, hz.z, hz.w};
    const float hnn[4] = {hn.x, hn.y, hn.z, hn.w};
    const float hvv[4] = {hv.x, hv.y, hv.z, hv.w};
#pragma unroll
    for (int i = 0; i < 4; ++i) {
        const float r = sigmoid_f(irr[i] + hrr[i]);
        const float z = sigmoid_f(izz[i] + hzz[i]);
        const float n = tanhf(fmaf(r, hnn[i], inn[i]));
        o[i] = fmaf(z, hvv[i] - n, n);
    }
    float4 ov = {o[0], o[1], o[2], o[3]};
    *(float4*)&h[(size_t)row * 128 + q] = ov;
    us4 ob;
    ob.x = f2bf(o[0]);
    ob.y = f2bf(o[1]);
    ob.z = f2bf(o[2]);
    ob.w = f2bf(o[3]);
    *(us4*)&h_bf[(size_t)row * 128 + q] = ob;
}

// ---------- fused pool + head: one block per batch ----------
__global__ void k_poolhead(const float* __restrict__ h,
                           const float* __restrict__ Wr1, const float* __restrict__ br1,
                           const float* __restrict__ Wr2, const float* __restrict__ br2,
                           const float* __restrict__ Wpol, const float* __restrict__ bpol,
                           float* __restrict__ out) {
    __shared__ float red[1024];
    __shared__ float p[128], t1[128];
    const int b = blockIdx.x, t = threadIdx.x;
    const int d = t & 127, ch = t >> 7;
    const float* hp = h + ((size_t)b * kN + ch * 128) * kD + d;
    float s = 0.f;
    for (int n = 0; n < 128; ++n) s += hp[(size_t)n * kD];
    red[t] = s;
    __syncthreads();
    if (t < 128) {
        float tot = 0.f;
        for (int c = 0; c < 8; ++c) tot += red[c * 128 + t];
        p[t] = tot;
    }
    __syncthreads();
    if (t < 128) {
        float acc = br1[t];
        for (int k = 0; k < 128; ++k) acc = fmaf(p[k], Wr1[k * 128 + t], acc);
        t1[t] = selu_f(acc);
    }
    __syncthreads();
    float acc2 = 0.f;
    if (t < 128) {
        acc2 = br2[t];
        for (int k = 0; k < 128; ++k) acc2 = fmaf(t1[k], Wr2[k * 128 + t], acc2);
    }
    __syncthreads();
    if (t < 128) p[t] = selu_f(acc2);
    __syncthreads();
    if (t < 64) {
        float o = bpol[t];
        for (int k = 0; k < 128; ++k) o = fmaf(p[k], Wpol[k * 64 + t], o);
        out[b * 64 + t] = o;
    }
}

extern "C" void kernel_launch(void* const* d_in, const int* in_sizes, int n_in,
                              void* d_out, int out_size, void* d_ws, size_t ws_size,
                              hipStream_t stream) {
    const float* nodef = (const float*)d_in[0];
    const float* edgef = (const float*)d_in[1];
    const int* src = (const int*)d_in[2];
    const int* tgt = (const int*)d_in[3];
    const float* Wmsg = (const float*)d_in[4];
    const float* bmsg = (const float*)d_in[5];
    const float* Wih = (const float*)d_in[6];
    const float* Whh = (const float*)d_in[7];
    const float* bih = (const float*)d_in[8];
    const float* bhh = (const float*)d_in[9];
    const float* Wr1 = (const float*)d_in[10];
    const float* br1 = (const float*)d_in[11];
    const float* Wr2 = (const float*)d_in[12];
    const float* br2 = (const float*)d_in[13];
    const float* Wpol = (const float*)d_in[14];
    const float* bpol = (const float*)d_in[15];
    float* out = (float*)d_out;

    float* ws = (float*)d_ws;
    float* gh = ws;                                     // 6,291,456 f
    float* gi = gh + 6291456;                           // 6,291,456 f
    float* h = gi + 6291456;                            // 2,097,152 f
    float* efg = h + 2097152;                           // 262,144 f
    unsigned short* HST = (unsigned short*)(efg + 262144);      // 4,194,304 e
    unsigned short* h_bf = HST + 4194304;               // 2,097,152 e
    unsigned short* agg_bf = h_bf + 2097152;            // 2,097,152 e
    unsigned short* WcatT = agg_bf + 2097152;           // 81,920 e
    unsigned short* WihB = WcatT + 81920;               // 49,152 e
    int* rowstart = (int*)(WihB + 49152);               // 1,040 (1025 used)
    int* sid = rowstart + 1040;                         // 16,384
    int* ssrc = sid + 16384;                            // 16,384

    k_h0<<<(kB * kN * kD) / 256, 256, 0, stream>>>(nodef, h, h_bf);
    k_sort<<<1, 1024, 0, stream>>>(src, tgt, rowstart, sid, ssrc);
    k_gather_ef<<<(kB * kE) / 256, 256, 0, stream>>>(edgef, src, tgt, sid, efg);
    k_buildw<<<640, 128, 0, stream>>>(Wmsg, Whh, Wih, WcatT, WihB);

    for (int it = 0; it < 3; ++it) {
        // [HS | HT] (bf16) and gh (fp32, +bhh) = h @ WcatT^T
        k_mm640<<<dim3(128, 5), 256, 0, stream>>>(h_bf, WcatT, bhh, HST, gh);
        // per-target selu-reduce over sorted edges -> agg (bf16)
        k_edge<<<dim3(kN / 8, kB), 256, 0, stream>>>(HST, efg, ssrc, rowstart, Wmsg, bmsg, agg_bf);
        // gi = agg @ Wih^T + bih
        k_mm384<<<dim3(128, 3), 256, 0, stream>>>(agg_bf, WihB, bih, gi);
        k_gru<<<(kB * kN * kD / 4) / 256, 256, 0, stream>>>(gi, gh, h, h_bf);
    }

    k_poolhead<<<kB, 1024, 0, stream>>>(h, Wr1, br1, Wr2, br2, Wpol, bpol, out);
}

// Round 6
// 345.983 us; speedup vs baseline: 1.0942x; 1.0942x over previous
//
#include <hip/hip_runtime.h>
#include <hip/hip_bf16.h>
#include <math.h>

constexpr int kB = 16;
constexpr int kN = 1024;
constexpr int kD = 128;
constexpr int kE = 16384;

typedef short bf16x8 __attribute__((ext_vector_type(8)));
typedef float f32x4 __attribute__((ext_vector_type(4)));
typedef unsigned short us4 __attribute__((ext_vector_type(4)));

__device__ __forceinline__ float selu_f(float x) {
    const float scale = 1.0507009873554805f;
    const float alpha = 1.6732632423543772f;
    return x > 0.f ? scale * x : scale * alpha * (expf(x) - 1.f);
}

__device__ __forceinline__ float sigmoid_f(float x) {
    return 1.f / (1.f + expf(-x));
}

__device__ __forceinline__ float bf2f(unsigned short u) {
    union { unsigned int i; float f; } x;
    x.i = ((unsigned int)u) << 16;
    return x.f;
}

// round-to-nearest-even f32 -> bf16
__device__ __forceinline__ unsigned short f2bf(float f) {
    union { float f; unsigned int i; } u;
    u.f = f;
    const unsigned int r = u.i + 0x7fffu + ((u.i >> 16) & 1u);
    return (unsigned short)(r >> 16);
}

// ---------- parallel sort-by-target ----------
__global__ void k_count(const int* __restrict__ tgt, int* __restrict__ cnt) {
    int e = blockIdx.x * 256 + threadIdx.x;
    atomicAdd(&cnt[tgt[e]], 1);
}

__global__ void k_scan(const int* __restrict__ cnt, int* __restrict__ cursor,
                       int* __restrict__ rowstart) {
    __shared__ int s[kN];
    int t = threadIdx.x;
    int own = cnt[t];
    s[t] = own;
    __syncthreads();
    for (int off = 1; off < kN; off <<= 1) {
        int add = (t >= off) ? s[t - off] : 0;
        __syncthreads();
        s[t] += add;
        __syncthreads();
    }
    int excl = s[t] - own;
    cursor[t] = excl;
    rowstart[t] = excl;
    if (t == kN - 1) rowstart[kN] = s[t];
}

__global__ void k_scatter(const int* __restrict__ src, const int* __restrict__ tgt,
                          int* __restrict__ cursor, int* __restrict__ sid,
                          int* __restrict__ ssrc) {
    int e = blockIdx.x * 256 + threadIdx.x;
    int tg = tgt[e];
    int pos = atomicAdd(&cursor[tg], 1);
    sid[pos] = e;
    ssrc[pos] = src[e];
}

__global__ void k_gather_ef(const float* __restrict__ edgef, const int* __restrict__ src,
                            const int* __restrict__ tgt, const int* __restrict__ sid,
                            float* __restrict__ efg) {
    int gid = blockIdx.x * 256 + threadIdx.x;  // < kB*kE
    int b = gid >> 14;
    int i = gid & (kE - 1);
    int eid = sid[i];
    efg[gid] = edgef[(size_t)b * kN * kN + (size_t)src[eid] * kN + tgt[eid]];
}

// h init: fp32 copy + bf16 shadow
__global__ void k_h0(const float* __restrict__ nodef, float* __restrict__ h,
                     unsigned short* __restrict__ h_bf) {
    int gid = blockIdx.x * 256 + threadIdx.x;
    float v = nodef[gid];
    h[gid] = v;
    h_bf[gid] = f2bf(v);
}

// WcatT[j][k] (640 x 128 bf16), j<128: W1^T, j<256: W2^T, j>=256: Whh raw rows.
// WihB[j][k] (384 x 128 bf16) = Wih raw rows.
__global__ void k_buildw(const float* __restrict__ Wmsg, const float* __restrict__ Whh,
                         const float* __restrict__ Wih,
                         unsigned short* __restrict__ WcatT, unsigned short* __restrict__ WihB) {
    int j = blockIdx.x;   // 640
    int k = threadIdx.x;  // 128
    float v;
    if (j < 128)      v = Wmsg[k * 128 + j];
    else if (j < 256) v = Wmsg[(128 + k) * 128 + (j - 128)];
    else              v = Whh[(size_t)(j - 256) * 128 + k];
    WcatT[j * 128 + k] = f2bf(v);
    if (j < 384) WihB[j * 128 + k] = f2bf(Wih[(size_t)j * 128 + k]);
}

// ---------- MFMA GEMM (h @ Wcat): cols<256 -> HST bf16, cols>=256 -> gh bf16 (+bhh)
__launch_bounds__(256)
__global__ void k_mm640(const unsigned short* __restrict__ A,
                        const unsigned short* __restrict__ Bt,
                        const float* __restrict__ bhh,
                        unsigned short* __restrict__ HST, unsigned short* __restrict__ ghb) {
    __shared__ uint4 As[2048];
    __shared__ uint4 Bs[2048];
    const int t = threadIdx.x;
    const int r0 = blockIdx.x * 128;
    const int c0 = blockIdx.y * 128;
    const uint4* gA = (const uint4*)(A + (size_t)r0 * 128);
    const uint4* gB = (const uint4*)(Bt + (size_t)c0 * 128);
#pragma unroll
    for (int i = 0; i < 8; ++i) {
        const int f = i * 256 + t;
        const int row = f >> 4, c16 = f & 15;
        const int d = row * 16 + (c16 ^ (row & 7));
        As[d] = gA[f];
        Bs[d] = gB[f];
    }
    __syncthreads();
    const int w = t >> 6, l = t & 63;
    const int wm = (w & 1) * 64, wn = (w >> 1) * 64;
    const int lin = l & 15, kq = l >> 4;
    f32x4 acc[4][4] = {};
#pragma unroll
    for (int s = 0; s < 4; ++s) {
        bf16x8 a[4], b[4];
#pragma unroll
        for (int mi = 0; mi < 4; ++mi) {
            const int row = wm + mi * 16 + lin;
            a[mi] = *(const bf16x8*)&As[row * 16 + ((s * 4 + kq) ^ (row & 7))];
        }
#pragma unroll
        for (int ni = 0; ni < 4; ++ni) {
            const int row = wn + ni * 16 + lin;
            b[ni] = *(const bf16x8*)&Bs[row * 16 + ((s * 4 + kq) ^ (row & 7))];
        }
#pragma unroll
        for (int mi = 0; mi < 4; ++mi)
#pragma unroll
            for (int ni = 0; ni < 4; ++ni)
                acc[mi][ni] = __builtin_amdgcn_mfma_f32_16x16x32_bf16(
                    a[mi], b[ni], acc[mi][ni], 0, 0, 0);
    }
    const int rq = kq * 4;
    if (c0 < 256) {
#pragma unroll
        for (int ni = 0; ni < 4; ++ni) {
            const int col = c0 + wn + ni * 16 + lin;
#pragma unroll
            for (int mi = 0; mi < 4; ++mi) {
                const int row = r0 + wm + mi * 16 + rq;
#pragma unroll
                for (int r = 0; r < 4; ++r)
                    HST[(size_t)(row + r) * 256 + col] = f2bf(acc[mi][ni][r]);
            }
        }
    } else {
#pragma unroll
        for (int ni = 0; ni < 4; ++ni) {
            const int gcol = (c0 - 256) + wn + ni * 16 + lin;
            const float bv = bhh[gcol];
#pragma unroll
            for (int mi = 0; mi < 4; ++mi) {
                const int row = r0 + wm + mi * 16 + rq;
#pragma unroll
                for (int r = 0; r < 4; ++r)
                    ghb[(size_t)(row + r) * 384 + gcol] = f2bf(acc[mi][ni][r] + bv);
            }
        }
    }
}

// ---------- MFMA GEMM: gi = agg_bf @ WihB^T + bih (bf16 out) ----------
__launch_bounds__(256)
__global__ void k_mm384(const unsigned short* __restrict__ A,
                        const unsigned short* __restrict__ Bt,
                        const float* __restrict__ bias, unsigned short* __restrict__ C) {
    __shared__ uint4 As[2048];
    __shared__ uint4 Bs[2048];
    const int t = threadIdx.x;
    const int r0 = blockIdx.x * 128;
    const int c0 = blockIdx.y * 128;
    const uint4* gA = (const uint4*)(A + (size_t)r0 * 128);
    const uint4* gB = (const uint4*)(Bt + (size_t)c0 * 128);
#pragma unroll
    for (int i = 0; i < 8; ++i) {
        const int f = i * 256 + t;
        const int row = f >> 4, c16 = f & 15;
        const int d = row * 16 + (c16 ^ (row & 7));
        As[d] = gA[f];
        Bs[d] = gB[f];
    }
    __syncthreads();
    const int w = t >> 6, l = t & 63;
    const int wm = (w & 1) * 64, wn = (w >> 1) * 64;
    const int lin = l & 15, kq = l >> 4;
    f32x4 acc[4][4] = {};
#pragma unroll
    for (int s = 0; s < 4; ++s) {
        bf16x8 a[4], b[4];
#pragma unroll
        for (int mi = 0; mi < 4; ++mi) {
            const int row = wm + mi * 16 + lin;
            a[mi] = *(const bf16x8*)&As[row * 16 + ((s * 4 + kq) ^ (row & 7))];
        }
#pragma unroll
        for (int ni = 0; ni < 4; ++ni) {
            const int row = wn + ni * 16 + lin;
            b[ni] = *(const bf16x8*)&Bs[row * 16 + ((s * 4 + kq) ^ (row & 7))];
        }
#pragma unroll
        for (int mi = 0; mi < 4; ++mi)
#pragma unroll
            for (int ni = 0; ni < 4; ++ni)
                acc[mi][ni] = __builtin_amdgcn_mfma_f32_16x16x32_bf16(
                    a[mi], b[ni], acc[mi][ni], 0, 0, 0);
    }
    const int rq = kq * 4;
#pragma unroll
    for (int ni = 0; ni < 4; ++ni) {
        const int col = c0 + wn + ni * 16 + lin;
        const float bv = bias[col];
#pragma unroll
        for (int mi = 0; mi < 4; ++mi) {
            const int row = r0 + wm + mi * 16 + rq;
#pragma unroll
            for (int r = 0; r < 4; ++r)
                C[(size_t)(row + r) * 384 + col] = f2bf(acc[mi][ni][r] + bv);
        }
    }
}

// ---------- per-target edge reduce: 8 targets/block, 32 lanes x 4 cols each ----------
__launch_bounds__(256)
__global__ void k_edge(const unsigned short* __restrict__ HST, const float* __restrict__ efg,
                       const int* __restrict__ ssrc, const int* __restrict__ rowstart,
                       const float* __restrict__ Wmsg, const float* __restrict__ bmsg,
                       unsigned short* __restrict__ agg_bf) {
    const int t = threadIdx.x;
    const int b = blockIdx.y;
    const int tg = blockIdx.x * 8 + (t >> 5);
    const int c = (t & 31) * 4;
    const float4 w3 = *(const float4*)&Wmsg[256 * 128 + c];
    const float4 bm = *(const float4*)&bmsg[c];
    const size_t base = (size_t)b * kN;
    const us4 htu = *(const us4*)&HST[(base + tg) * 256 + 128 + c];
    const float hb0 = bf2f(htu.x) + bm.x;
    const float hb1 = bf2f(htu.y) + bm.y;
    const float hb2 = bf2f(htu.z) + bm.z;
    const float hb3 = bf2f(htu.w) + bm.w;
    const float* efb = efg + b * kE;
    const int j0 = rowstart[tg], j1 = rowstart[tg + 1];
    float a0 = 0.f, a1 = 0.f, a2 = 0.f, a3 = 0.f;
    int j = j0;
    us4 hsn = {};
    float efn = 0.f;
    if (j < j1) {
        const int s = ssrc[j];
        efn = efb[j];
        hsn = *(const us4*)&HST[(base + s) * 256 + c];
    }
    while (j < j1) {
        const us4 hs = hsn;
        const float ef = efn;
        const int jn = j + 1;
        if (jn < j1) {
            const int s2 = ssrc[jn];
            efn = efb[jn];
            hsn = *(const us4*)&HST[(base + s2) * 256 + c];
        }
        a0 += selu_f(bf2f(hs.x) + fmaf(ef, w3.x, hb0));
        a1 += selu_f(bf2f(hs.y) + fmaf(ef, w3.y, hb1));
        a2 += selu_f(bf2f(hs.z) + fmaf(ef, w3.z, hb2));
        a3 += selu_f(bf2f(hs.w) + fmaf(ef, w3.w, hb3));
        j = jn;
    }
    us4 o;
    o.x = f2bf(a0);
    o.y = f2bf(a1);
    o.z = f2bf(a2);
    o.w = f2bf(a3);
    *(us4*)&agg_bf[(base + tg) * 128 + c] = o;
}

// ---------- elementwise GRU (gi/gh bf16 in) ----------
__global__ void k_gru(const unsigned short* __restrict__ gib,
                      const unsigned short* __restrict__ ghb,
                      float* __restrict__ h, unsigned short* __restrict__ h_bf) {
    const int gid = blockIdx.x * 256 + threadIdx.x;  // < kB*kN*kD/4
    const int row = gid >> 5, q = (gid & 31) * 4;
    const unsigned short* gir = gib + (size_t)row * 384;
    const unsigned short* ghr = ghb + (size_t)row * 384;
    const us4 ir = *(const us4*)&gir[q];
    const us4 iz = *(const us4*)&gir[q + 128];
    const us4 in = *(const us4*)&gir[q + 256];
    const us4 hr = *(const us4*)&ghr[q];
    const us4 hz = *(const us4*)&ghr[q + 128];
    const us4 hn = *(const us4*)&ghr[q + 256];
    float4 hv = *(const float4*)&h[(size_t)row * 128 + q];
    const float irr[4] = {bf2f(ir.x), bf2f(ir.y), bf2f(ir.z), bf2f(ir.w)};
    const float izz[4] = {bf2f(iz.x), bf2f(iz.y), bf2f(iz.z), bf2f(iz.w)};
    const float inn[4] = {bf2f(in.x), bf2f(in.y), bf2f(in.z), bf2f(in.w)};
    const float hrr[4] = {bf2f(hr.x), bf2f(hr.y), bf2f(hr.z), bf2f(hr.w)};
    const float hzz[4] = {bf2f(hz.x), bf2f(hz.y), bf2f(hz.z), bf2f(hz.w)};
    const float hnn[4] = {bf2f(hn.x), bf2f(hn.y), bf2f(hn.z), bf2f(hn.w)};
    const float hvv[4] = {hv.x, hv.y, hv.z, hv.w};
    float o[4];
#pragma unroll
    for (int i = 0; i < 4; ++i) {
        const float r = sigmoid_f(irr[i] + hrr[i]);
        const float z = sigmoid_f(izz[i] + hzz[i]);
        const float n = tanhf(fmaf(r, hnn[i], inn[i]));
        o[i] = fmaf(z, hvv[i] - n, n);
    }
    float4 ov = {o[0], o[1], o[2], o[3]};
    *(float4*)&h[(size_t)row * 128 + q] = ov;
    us4 ob;
    ob.x = f2bf(o[0]);
    ob.y = f2bf(o[1]);
    ob.z = f2bf(o[2]);
    ob.w = f2bf(o[3]);
    *(us4*)&h_bf[(size_t)row * 128 + q] = ob;
}

// ---------- fused pool + head ----------
__global__ void k_poolhead(const float* __restrict__ h,
                           const float* __restrict__ Wr1, const float* __restrict__ br1,
                           const float* __restrict__ Wr2, const float* __restrict__ br2,
                           const float* __restrict__ Wpol, const float* __restrict__ bpol,
                           float* __restrict__ out) {
    __shared__ float red[1024];
    __shared__ float p[128], t1[128];
    const int b = blockIdx.x, t = threadIdx.x;
    const int d = t & 127, ch = t >> 7;
    const float* hp = h + ((size_t)b * kN + ch * 128) * kD + d;
    float s = 0.f;
    for (int n = 0; n < 128; ++n) s += hp[(size_t)n * kD];
    red[t] = s;
    __syncthreads();
    if (t < 128) {
        float tot = 0.f;
        for (int c = 0; c < 8; ++c) tot += red[c * 128 + t];
        p[t] = tot;
    }
    __syncthreads();
    if (t < 128) {
        float acc = br1[t];
        for (int k = 0; k < 128; ++k) acc = fmaf(p[k], Wr1[k * 128 + t], acc);
        t1[t] = selu_f(acc);
    }
    __syncthreads();
    float acc2 = 0.f;
    if (t < 128) {
        acc2 = br2[t];
        for (int k = 0; k < 128; ++k) acc2 = fmaf(t1[k], Wr2[k * 128 + t], acc2);
    }
    __syncthreads();
    if (t < 128) p[t] = selu_f(acc2);
    __syncthreads();
    if (t < 64) {
        float o = bpol[t];
        for (int k = 0; k < 128; ++k) o = fmaf(p[k], Wpol[k * 64 + t], o);
        out[b * 64 + t] = o;
    }
}

extern "C" void kernel_launch(void* const* d_in, const int* in_sizes, int n_in,
                              void* d_out, int out_size, void* d_ws, size_t ws_size,
                              hipStream_t stream) {
    const float* nodef = (const float*)d_in[0];
    const float* edgef = (const float*)d_in[1];
    const int* src = (const int*)d_in[2];
    const int* tgt = (const int*)d_in[3];
    const float* Wmsg = (const float*)d_in[4];
    const float* bmsg = (const float*)d_in[5];
    const float* Wih = (const float*)d_in[6];
    const float* Whh = (const float*)d_in[7];
    const float* bih = (const float*)d_in[8];
    const float* bhh = (const float*)d_in[9];
    const float* Wr1 = (const float*)d_in[10];
    const float* br1 = (const float*)d_in[11];
    const float* Wr2 = (const float*)d_in[12];
    const float* br2 = (const float*)d_in[13];
    const float* Wpol = (const float*)d_in[14];
    const float* bpol = (const float*)d_in[15];
    float* out = (float*)d_out;

    float* ws = (float*)d_ws;
    float* h = ws;                                      // 2,097,152 f
    float* efg = h + 2097152;                           // 262,144 f
    unsigned short* ghb = (unsigned short*)(efg + 262144);      // 6,291,456 e
    unsigned short* gib = ghb + 6291456;                // 6,291,456 e
    unsigned short* HST = gib + 6291456;                // 4,194,304 e
    unsigned short* h_bf = HST + 4194304;               // 2,097,152 e
    unsigned short* agg_bf = h_bf + 2097152;            // 2,097,152 e
    unsigned short* WcatT = agg_bf + 2097152;           // 81,920 e
    unsigned short* WihB = WcatT + 81920;               // 49,152 e
    int* cnt = (int*)(WihB + 49152);                    // 1,024
    int* cursor = cnt + 1024;                           // 1,024
    int* rowstart = cursor + 1024;                      // 1,040 (1025 used)
    int* sid = rowstart + 1040;                         // 16,384
    int* ssrc = sid + 16384;                            // 16,384

    hipMemsetAsync(cnt, 0, 1024 * sizeof(int), stream);
    k_h0<<<(kB * kN * kD) / 256, 256, 0, stream>>>(nodef, h, h_bf);
    k_count<<<kE / 256, 256, 0, stream>>>(tgt, cnt);
    k_scan<<<1, 1024, 0, stream>>>(cnt, cursor, rowstart);
    k_scatter<<<kE / 256, 256, 0, stream>>>(src, tgt, cursor, sid, ssrc);
    k_gather_ef<<<(kB * kE) / 256, 256, 0, stream>>>(edgef, src, tgt, sid, efg);
    k_buildw<<<640, 128, 0, stream>>>(Wmsg, Whh, Wih, WcatT, WihB);

    for (int it = 0; it < 3; ++it) {
        // [HS | HT] (bf16) and gh (bf16, +bhh) = h @ WcatT^T
        k_mm640<<<dim3(128, 5), 256, 0, stream>>>(h_bf, WcatT, bhh, HST, ghb);
        // per-target selu-reduce over sorted edges -> agg (bf16)
        k_edge<<<dim3(kN / 8, kB), 256, 0, stream>>>(HST, efg, ssrc, rowstart, Wmsg, bmsg, agg_bf);
        // gi = agg @ Wih^T + bih (bf16 out)
        k_mm384<<<dim3(128, 3), 256, 0, stream>>>(agg_bf, WihB, bih, gib);
        k_gru<<<(kB * kN * kD / 4) / 256, 256, 0, stream>>>(gib, ghb, h, h_bf);
    }

    k_poolhead<<<kB, 1024, 0, stream>>>(h, Wr1, br1, Wr2, br2, Wpol, bpol, out);
}

// Round 7
// 331.005 us; speedup vs baseline: 1.1437x; 1.0452x over previous
//
#include <hip/hip_runtime.h>
#include <hip/hip_bf16.h>
#include <math.h>

constexpr int kB = 16;
constexpr int kN = 1024;
constexpr int kD = 128;
constexpr int kE = 16384;

typedef short bf16x8 __attribute__((ext_vector_type(8)));
typedef float f32x4 __attribute__((ext_vector_type(4)));
typedef unsigned short us4 __attribute__((ext_vector_type(4)));

__device__ __forceinline__ float selu_f(float x) {
    const float scale = 1.0507009873554805f;
    const float alpha = 1.6732632423543772f;
    return x > 0.f ? scale * x : scale * alpha * (expf(x) - 1.f);
}

__device__ __forceinline__ float sigmoid_f(float x) {
    return 1.f / (1.f + expf(-x));
}

__device__ __forceinline__ float bf2f(unsigned short u) {
    union { unsigned int i; float f; } x;
    x.i = ((unsigned int)u) << 16;
    return x.f;
}

// round-to-nearest-even f32 -> bf16
__device__ __forceinline__ unsigned short f2bf(float f) {
    union { float f; unsigned int i; } u;
    u.f = f;
    const unsigned int r = u.i + 0x7fffu + ((u.i >> 16) & 1u);
    return (unsigned short)(r >> 16);
}

// ---------- parallel sort-by-target ----------
__global__ void k_count(const int* __restrict__ tgt, int* __restrict__ cnt) {
    int e = blockIdx.x * 256 + threadIdx.x;
    atomicAdd(&cnt[tgt[e]], 1);
}

__global__ void k_scan(const int* __restrict__ cnt, int* __restrict__ cursor,
                       int* __restrict__ rowstart) {
    __shared__ int s[kN];
    int t = threadIdx.x;
    int own = cnt[t];
    s[t] = own;
    __syncthreads();
    for (int off = 1; off < kN; off <<= 1) {
        int add = (t >= off) ? s[t - off] : 0;
        __syncthreads();
        s[t] += add;
        __syncthreads();
    }
    int excl = s[t] - own;
    cursor[t] = excl;
    rowstart[t] = excl;
    if (t == kN - 1) rowstart[kN] = s[t];
}

__global__ void k_scatter(const int* __restrict__ src, const int* __restrict__ tgt,
                          int* __restrict__ cursor, int* __restrict__ sid,
                          int* __restrict__ ssrc) {
    int e = blockIdx.x * 256 + threadIdx.x;
    int tg = tgt[e];
    int pos = atomicAdd(&cursor[tg], 1);
    sid[pos] = e;
    ssrc[pos] = src[e];
}

__global__ void k_gather_ef(const float* __restrict__ edgef, const int* __restrict__ src,
                            const int* __restrict__ tgt, const int* __restrict__ sid,
                            float* __restrict__ efg) {
    int gid = blockIdx.x * 256 + threadIdx.x;  // < kB*kE
    int b = gid >> 14;
    int i = gid & (kE - 1);
    int eid = sid[i];
    efg[gid] = edgef[(size_t)b * kN * kN + (size_t)src[eid] * kN + tgt[eid]];
}

// h init: fp32 copy + bf16 shadow
__global__ void k_h0(const float* __restrict__ nodef, float* __restrict__ h,
                     unsigned short* __restrict__ h_bf) {
    int gid = blockIdx.x * 256 + threadIdx.x;
    float v = nodef[gid];
    h[gid] = v;
    h_bf[gid] = f2bf(v);
}

// Weight prep:
//  WcatT[j][k] (256 x 128): j<128 -> W1^T (Wmsg src rows), j<256 -> W2^T.
//  Wfused[f][256] (384 x 256): gate-interleaved col' f = dg*48 + g*16 + di
//    <-> orig col = g*128 + dg*16 + di.  k<128: Wih[orig][k]; k>=128: Whh[orig][k-128].
//  bihP/bhhP: biases permuted to col' order.
__global__ void k_buildw(const float* __restrict__ Wmsg, const float* __restrict__ Whh,
                         const float* __restrict__ Wih,
                         const float* __restrict__ bih, const float* __restrict__ bhh,
                         unsigned short* __restrict__ WcatT,
                         unsigned short* __restrict__ Wfused,
                         float* __restrict__ bihP, float* __restrict__ bhhP) {
    const int j = blockIdx.x;   // 640
    const int k = threadIdx.x;  // 128
    if (j < 256) {
        float v = (j < 128) ? Wmsg[k * 128 + j] : Wmsg[(128 + k) * 128 + (j - 128)];
        WcatT[j * 128 + k] = f2bf(v);
    } else {
        const int f = j - 256;                 // col' in [0,384)
        const int dg = f / 48, rem = f % 48;
        const int g = rem / 16, di = rem % 16;
        const int orig = g * 128 + dg * 16 + di;
        Wfused[(size_t)f * 256 + k] = f2bf(Wih[(size_t)orig * 128 + k]);
        Wfused[(size_t)f * 256 + 128 + k] = f2bf(Whh[(size_t)orig * 128 + k]);
        if (k == 0) {
            bihP[f] = bih[orig];
            bhhP[f] = bhh[orig];
        }
    }
}

// ---------- MFMA GEMM: HST[.][256] = h_bf @ WcatT^T (bf16 out, no bias) ----------
__launch_bounds__(256)
__global__ void k_mm256(const unsigned short* __restrict__ A,
                        const unsigned short* __restrict__ Bt,
                        unsigned short* __restrict__ HST) {
    __shared__ uint4 As[2048];
    __shared__ uint4 Bs[2048];
    const int t = threadIdx.x;
    const int r0 = blockIdx.x * 128;
    const int c0 = blockIdx.y * 128;
    const uint4* gA = (const uint4*)(A + (size_t)r0 * 128);
    const uint4* gB = (const uint4*)(Bt + (size_t)c0 * 128);
#pragma unroll
    for (int i = 0; i < 8; ++i) {
        const int f = i * 256 + t;
        const int row = f >> 4, c16 = f & 15;
        const int d = row * 16 + (c16 ^ (row & 7));
        As[d] = gA[f];
        Bs[d] = gB[f];
    }
    __syncthreads();
    const int w = t >> 6, l = t & 63;
    const int wm = (w & 1) * 64, wn = (w >> 1) * 64;
    const int lin = l & 15, kq = l >> 4;
    f32x4 acc[4][4] = {};
#pragma unroll
    for (int s = 0; s < 4; ++s) {
        bf16x8 a[4], b[4];
#pragma unroll
        for (int mi = 0; mi < 4; ++mi) {
            const int row = wm + mi * 16 + lin;
            a[mi] = *(const bf16x8*)&As[row * 16 + ((s * 4 + kq) ^ (row & 7))];
        }
#pragma unroll
        for (int ni = 0; ni < 4; ++ni) {
            const int row = wn + ni * 16 + lin;
            b[ni] = *(const bf16x8*)&Bs[row * 16 + ((s * 4 + kq) ^ (row & 7))];
        }
#pragma unroll
        for (int mi = 0; mi < 4; ++mi)
#pragma unroll
            for (int ni = 0; ni < 4; ++ni)
                acc[mi][ni] = __builtin_amdgcn_mfma_f32_16x16x32_bf16(
                    a[mi], b[ni], acc[mi][ni], 0, 0, 0);
    }
    const int rq = kq * 4;
#pragma unroll
    for (int ni = 0; ni < 4; ++ni) {
        const int col = c0 + wn + ni * 16 + lin;
#pragma unroll
        for (int mi = 0; mi < 4; ++mi) {
            const int row = r0 + wm + mi * 16 + rq;
#pragma unroll
            for (int r = 0; r < 4; ++r)
                HST[(size_t)(row + r) * 256 + col] = f2bf(acc[mi][ni][r]);
        }
    }
}

// ---------- per-target edge reduce -> agg (bf16) ----------
__launch_bounds__(256)
__global__ void k_edge(const unsigned short* __restrict__ HST, const float* __restrict__ efg,
                       const int* __restrict__ ssrc, const int* __restrict__ rowstart,
                       const float* __restrict__ Wmsg, const float* __restrict__ bmsg,
                       unsigned short* __restrict__ agg_bf) {
    const int t = threadIdx.x;
    const int b = blockIdx.y;
    const int tg = blockIdx.x * 8 + (t >> 5);
    const int c = (t & 31) * 4;
    const float4 w3 = *(const float4*)&Wmsg[256 * 128 + c];
    const float4 bm = *(const float4*)&bmsg[c];
    const size_t base = (size_t)b * kN;
    const us4 htu = *(const us4*)&HST[(base + tg) * 256 + 128 + c];
    const float hb0 = bf2f(htu.x) + bm.x;
    const float hb1 = bf2f(htu.y) + bm.y;
    const float hb2 = bf2f(htu.z) + bm.z;
    const float hb3 = bf2f(htu.w) + bm.w;
    const float* efb = efg + b * kE;
    const int j0 = rowstart[tg], j1 = rowstart[tg + 1];
    float a0 = 0.f, a1 = 0.f, a2 = 0.f, a3 = 0.f;
    int j = j0;
    us4 hsn = {};
    float efn = 0.f;
    if (j < j1) {
        const int s = ssrc[j];
        efn = efb[j];
        hsn = *(const us4*)&HST[(base + s) * 256 + c];
    }
    while (j < j1) {
        const us4 hs = hsn;
        const float ef = efn;
        const int jn = j + 1;
        if (jn < j1) {
            const int s2 = ssrc[jn];
            efn = efb[jn];
            hsn = *(const us4*)&HST[(base + s2) * 256 + c];
        }
        a0 += selu_f(bf2f(hs.x) + fmaf(ef, w3.x, hb0));
        a1 += selu_f(bf2f(hs.y) + fmaf(ef, w3.y, hb1));
        a2 += selu_f(bf2f(hs.z) + fmaf(ef, w3.z, hb2));
        a3 += selu_f(bf2f(hs.w) + fmaf(ef, w3.w, hb3));
        j = jn;
    }
    us4 o;
    o.x = f2bf(a0);
    o.y = f2bf(a1);
    o.z = f2bf(a2);
    o.w = f2bf(a3);
    *(us4*)&agg_bf[(base + tg) * 128 + c] = o;
}

// ---------- fused gi-GEMM + gh-GEMM + GRU ----------
// C'[row][col'] with gate-interleaved col' = dg*48 + g*16 + di.
// Block: 128 rows x 96 col' (= 32 d's, all 3 gates). Grid (16384/128, 4).
// Stage 0: A=agg_bf, B=Wfused[.][0:128] (Wih');  stage 1: A=h_bf, B=Wfused[.][128:256] (Whh').
// r,z gates accumulate across both stages; n gate: stage0 -> acc (i_n), stage1 -> accN (h_n).
// Epilogue: GRU, writes h fp32 + h_bf.
__launch_bounds__(256)
__global__ void k_gigru(const unsigned short* __restrict__ agg_bf,
                        const unsigned short* __restrict__ h_bf_in,
                        const unsigned short* __restrict__ Wfused,
                        const float* __restrict__ bihP, const float* __restrict__ bhhP,
                        float* __restrict__ h, unsigned short* __restrict__ h_bf_out) {
    __shared__ uint4 As[2048];  // 128 x 128 bf16
    __shared__ uint4 Bs[1536];  // 96 x 128 bf16
    const int t = threadIdx.x;
    const int r0 = blockIdx.x * 128;
    const int y = blockIdx.y;  // [0,4): 96 col' each
    const int w = t >> 6, l = t & 63;
    const int wm = (w & 1) * 64, wc0 = (w >> 1) * 48;
    const int lin = l & 15, kq = l >> 4, rq = kq * 4;
    f32x4 acc[4][3] = {};
    f32x4 accN[4] = {};
#pragma unroll
    for (int stage = 0; stage < 2; ++stage) {
        const unsigned short* Ap = stage ? h_bf_in : agg_bf;
        const uint4* gA = (const uint4*)(Ap + (size_t)r0 * 128);
#pragma unroll
        for (int i = 0; i < 8; ++i) {
            const int f = i * 256 + t;
            const int row = f >> 4, c16 = f & 15;
            As[row * 16 + (c16 ^ (row & 7))] = gA[f];
        }
        const uint4* gW = (const uint4*)Wfused;  // [384][32] chunks
#pragma unroll
        for (int i = 0; i < 6; ++i) {
            const int f = i * 256 + t;  // < 1536
            const int j = f >> 4, c16 = f & 15;
            Bs[j * 16 + (c16 ^ (j & 7))] = gW[(size_t)(y * 96 + j) * 32 + stage * 16 + c16];
        }
        __syncthreads();
#pragma unroll
        for (int ks = 0; ks < 4; ++ks) {
            bf16x8 a[4], b[3];
#pragma unroll
            for (int mi = 0; mi < 4; ++mi) {
                const int row = wm + mi * 16 + lin;
                a[mi] = *(const bf16x8*)&As[row * 16 + ((ks * 4 + kq) ^ (row & 7))];
            }
#pragma unroll
            for (int ni = 0; ni < 3; ++ni) {
                const int row = wc0 + ni * 16 + lin;
                b[ni] = *(const bf16x8*)&Bs[row * 16 + ((ks * 4 + kq) ^ (row & 7))];
            }
#pragma unroll
            for (int mi = 0; mi < 4; ++mi) {
                acc[mi][0] = __builtin_amdgcn_mfma_f32_16x16x32_bf16(a[mi], b[0], acc[mi][0], 0, 0, 0);
                acc[mi][1] = __builtin_amdgcn_mfma_f32_16x16x32_bf16(a[mi], b[1], acc[mi][1], 0, 0, 0);
                if (stage == 0)
                    acc[mi][2] = __builtin_amdgcn_mfma_f32_16x16x32_bf16(a[mi], b[2], acc[mi][2], 0, 0, 0);
                else
                    accN[mi] = __builtin_amdgcn_mfma_f32_16x16x32_bf16(a[mi], b[2], accN[mi], 0, 0, 0);
            }
        }
        __syncthreads();
    }
    // epilogue: GRU
    const int colR = y * 96 + wc0 + lin;  // col' of r-gate
    const float bR = bihP[colR] + bhhP[colR];
    const float bZ = bihP[colR + 16] + bhhP[colR + 16];
    const float biN = bihP[colR + 32];
    const float bhN = bhhP[colR + 32];
    const int dgg = y * 2 + (wc0 / 48);
    const int d = dgg * 16 + lin;  // h column
#pragma unroll
    for (int mi = 0; mi < 4; ++mi) {
#pragma unroll
        for (int r = 0; r < 4; ++r) {
            const int row = r0 + wm + mi * 16 + rq + r;
            const float rr = sigmoid_f(acc[mi][0][r] + bR);
            const float zz = sigmoid_f(acc[mi][1][r] + bZ);
            const float i_n = acc[mi][2][r] + biN;
            const float h_n = accN[mi][r] + bhN;
            const float nn = tanhf(fmaf(rr, h_n, i_n));
            const size_t idx = (size_t)row * 128 + d;
            const float hv = h[idx];
            const float o = fmaf(zz, hv - nn, nn);
            h[idx] = o;
            h_bf_out[idx] = f2bf(o);
        }
    }
}

// ---------- fused pool + head ----------
__global__ void k_poolhead(const float* __restrict__ h,
                           const float* __restrict__ Wr1, const float* __restrict__ br1,
                           const float* __restrict__ Wr2, const float* __restrict__ br2,
                           const float* __restrict__ Wpol, const float* __restrict__ bpol,
                           float* __restrict__ out) {
    __shared__ float red[1024];
    __shared__ float p[128], t1[128];
    const int b = blockIdx.x, t = threadIdx.x;
    const int d = t & 127, ch = t >> 7;
    const float* hp = h + ((size_t)b * kN + ch * 128) * kD + d;
    float s = 0.f;
    for (int n = 0; n < 128; ++n) s += hp[(size_t)n * kD];
    red[t] = s;
    __syncthreads();
    if (t < 128) {
        float tot = 0.f;
        for (int c = 0; c < 8; ++c) tot += red[c * 128 + t];
        p[t] = tot;
    }
    __syncthreads();
    if (t < 128) {
        float acc = br1[t];
        for (int k = 0; k < 128; ++k) acc = fmaf(p[k], Wr1[k * 128 + t], acc);
        t1[t] = selu_f(acc);
    }
    __syncthreads();
    float acc2 = 0.f;
    if (t < 128) {
        acc2 = br2[t];
        for (int k = 0; k < 128; ++k) acc2 = fmaf(t1[k], Wr2[k * 128 + t], acc2);
    }
    __syncthreads();
    if (t < 128) p[t] = selu_f(acc2);
    __syncthreads();
    if (t < 64) {
        float o = bpol[t];
        for (int k = 0; k < 128; ++k) o = fmaf(p[k], Wpol[k * 64 + t], o);
        out[b * 64 + t] = o;
    }
}

extern "C" void kernel_launch(void* const* d_in, const int* in_sizes, int n_in,
                              void* d_out, int out_size, void* d_ws, size_t ws_size,
                              hipStream_t stream) {
    const float* nodef = (const float*)d_in[0];
    const float* edgef = (const float*)d_in[1];
    const int* src = (const int*)d_in[2];
    const int* tgt = (const int*)d_in[3];
    const float* Wmsg = (const float*)d_in[4];
    const float* bmsg = (const float*)d_in[5];
    const float* Wih = (const float*)d_in[6];
    const float* Whh = (const float*)d_in[7];
    const float* bih = (const float*)d_in[8];
    const float* bhh = (const float*)d_in[9];
    const float* Wr1 = (const float*)d_in[10];
    const float* br1 = (const float*)d_in[11];
    const float* Wr2 = (const float*)d_in[12];
    const float* br2 = (const float*)d_in[13];
    const float* Wpol = (const float*)d_in[14];
    const float* bpol = (const float*)d_in[15];
    float* out = (float*)d_out;

    float* ws = (float*)d_ws;
    float* h = ws;                                      // 2,097,152 f
    float* efg = h + 2097152;                           // 262,144 f
    float* bihP = efg + 262144;                         // 384 f
    float* bhhP = bihP + 384;                           // 384 f
    unsigned short* HST = (unsigned short*)(bhhP + 384);        // 4,194,304 e
    unsigned short* h_bf = HST + 4194304;               // 2,097,152 e
    unsigned short* agg_bf = h_bf + 2097152;            // 2,097,152 e
    unsigned short* WcatT = agg_bf + 2097152;           // 32,768 e
    unsigned short* Wfused = WcatT + 32768;             // 98,304 e
    int* cnt = (int*)(Wfused + 98304);                  // 1,024
    int* cursor = cnt + 1024;                           // 1,024
    int* rowstart = cursor + 1024;                      // 1,040 (1025 used)
    int* sid = rowstart + 1040;                         // 16,384
    int* ssrc = sid + 16384;                            // 16,384

    hipMemsetAsync(cnt, 0, 1024 * sizeof(int), stream);
    k_h0<<<(kB * kN * kD) / 256, 256, 0, stream>>>(nodef, h, h_bf);
    k_count<<<kE / 256, 256, 0, stream>>>(tgt, cnt);
    k_scan<<<1, 1024, 0, stream>>>(cnt, cursor, rowstart);
    k_scatter<<<kE / 256, 256, 0, stream>>>(src, tgt, cursor, sid, ssrc);
    k_gather_ef<<<(kB * kE) / 256, 256, 0, stream>>>(edgef, src, tgt, sid, efg);
    k_buildw<<<640, 128, 0, stream>>>(Wmsg, Whh, Wih, bih, bhh, WcatT, Wfused, bihP, bhhP);

    for (int it = 0; it < 3; ++it) {
        // [HS | HT] (bf16) = h @ [W1 | W2]
        k_mm256<<<dim3(128, 2), 256, 0, stream>>>(h_bf, WcatT, HST);
        // per-target selu-reduce over sorted edges -> agg (bf16)
        k_edge<<<dim3(kN / 8, kB), 256, 0, stream>>>(HST, efg, ssrc, rowstart, Wmsg, bmsg, agg_bf);
        // gi = agg@Wih^T+bih, gh = h@Whh^T+bhh (in registers) -> GRU -> h, h_bf
        k_gigru<<<dim3(128, 4), 256, 0, stream>>>(agg_bf, h_bf, Wfused, bihP, bhhP, h, h_bf);
    }

    k_poolhead<<<kB, 1024, 0, stream>>>(h, Wr1, br1, Wr2, br2, Wpol, bpol, out);
}

// Round 8
// 312.729 us; speedup vs baseline: 1.2105x; 1.0584x over previous
//
#include <hip/hip_runtime.h>
#include <hip/hip_bf16.h>
#include <math.h>

constexpr int kB = 16;
constexpr int kN = 1024;
constexpr int kD = 128;
constexpr int kE = 16384;

typedef short bf16x8 __attribute__((ext_vector_type(8)));
typedef float f32x4 __attribute__((ext_vector_type(4)));
typedef unsigned short us4 __attribute__((ext_vector_type(4)));

__device__ __forceinline__ float selu_f(float x) {
    const float scale = 1.0507009873554805f;
    const float alpha = 1.6732632423543772f;
    return x > 0.f ? scale * x : scale * alpha * (expf(x) - 1.f);
}

__device__ __forceinline__ float sigmoid_f(float x) {
    return 1.f / (1.f + expf(-x));
}

__device__ __forceinline__ float bf2f(unsigned short u) {
    union { unsigned int i; float f; } x;
    x.i = ((unsigned int)u) << 16;
    return x.f;
}

// round-to-nearest-even f32 -> bf16
__device__ __forceinline__ unsigned short f2bf(float f) {
    union { float f; unsigned int i; } u;
    u.f = f;
    const unsigned int r = u.i + 0x7fffu + ((u.i >> 16) & 1u);
    return (unsigned short)(r >> 16);
}

// ---------- parallel sort-by-target ----------
__global__ void k_count(const int* __restrict__ tgt, int* __restrict__ cnt) {
    int e = blockIdx.x * 256 + threadIdx.x;
    atomicAdd(&cnt[tgt[e]], 1);
}

__global__ void k_scan(const int* __restrict__ cnt, int* __restrict__ cursor,
                       int* __restrict__ rowstart) {
    __shared__ int s[kN];
    int t = threadIdx.x;
    int own = cnt[t];
    s[t] = own;
    __syncthreads();
    for (int off = 1; off < kN; off <<= 1) {
        int add = (t >= off) ? s[t - off] : 0;
        __syncthreads();
        s[t] += add;
        __syncthreads();
    }
    int excl = s[t] - own;
    cursor[t] = excl;
    rowstart[t] = excl;
    if (t == kN - 1) rowstart[kN] = s[t];
}

__global__ void k_scatter(const int* __restrict__ src, const int* __restrict__ tgt,
                          int* __restrict__ cursor, int* __restrict__ sid,
                          int* __restrict__ ssrc) {
    int e = blockIdx.x * 256 + threadIdx.x;
    int tg = tgt[e];
    int pos = atomicAdd(&cursor[tg], 1);
    sid[pos] = e;
    ssrc[pos] = src[e];
}

__global__ void k_gather_ef(const float* __restrict__ edgef, const int* __restrict__ src,
                            const int* __restrict__ tgt, const int* __restrict__ sid,
                            float* __restrict__ efg) {
    int gid = blockIdx.x * 256 + threadIdx.x;  // < kB*kE
    int b = gid >> 14;
    int i = gid & (kE - 1);
    int eid = sid[i];
    efg[gid] = edgef[(size_t)b * kN * kN + (size_t)src[eid] * kN + tgt[eid]];
}

// h init: fp32 copy + bf16 shadow
__global__ void k_h0(const float* __restrict__ nodef, float* __restrict__ h,
                     unsigned short* __restrict__ h_bf) {
    int gid = blockIdx.x * 256 + threadIdx.x;
    float v = nodef[gid];
    h[gid] = v;
    h_bf[gid] = f2bf(v);
}

// Weight prep (see R7 comments).
__global__ void k_buildw(const float* __restrict__ Wmsg, const float* __restrict__ Whh,
                         const float* __restrict__ Wih,
                         const float* __restrict__ bih, const float* __restrict__ bhh,
                         unsigned short* __restrict__ WcatT,
                         unsigned short* __restrict__ Wfused,
                         float* __restrict__ bihP, float* __restrict__ bhhP) {
    const int j = blockIdx.x;   // 640
    const int k = threadIdx.x;  // 128
    if (j < 256) {
        float v = (j < 128) ? Wmsg[k * 128 + j] : Wmsg[(128 + k) * 128 + (j - 128)];
        WcatT[j * 128 + k] = f2bf(v);
    } else {
        const int f = j - 256;                 // col' in [0,384)
        const int dg = f / 48, rem = f % 48;
        const int g = rem / 16, di = rem % 16;
        const int orig = g * 128 + dg * 16 + di;
        Wfused[(size_t)f * 256 + k] = f2bf(Wih[(size_t)orig * 128 + k]);
        Wfused[(size_t)f * 256 + 128 + k] = f2bf(Whh[(size_t)orig * 128 + k]);
        if (k == 0) {
            bihP[f] = bih[orig];
            bhhP[f] = bhh[orig];
        }
    }
}

// ---------- MFMA GEMM: HST[.][256] = h_bf @ WcatT^T (bf16 out, no bias) ----------
__launch_bounds__(256)
__global__ void k_mm256(const unsigned short* __restrict__ A,
                        const unsigned short* __restrict__ Bt,
                        unsigned short* __restrict__ HST) {
    __shared__ uint4 As[2048];
    __shared__ uint4 Bs[2048];
    const int t = threadIdx.x;
    const int r0 = blockIdx.x * 128;
    const int c0 = blockIdx.y * 128;
    const uint4* gA = (const uint4*)(A + (size_t)r0 * 128);
    const uint4* gB = (const uint4*)(Bt + (size_t)c0 * 128);
#pragma unroll
    for (int i = 0; i < 8; ++i) {
        const int f = i * 256 + t;
        const int row = f >> 4, c16 = f & 15;
        const int d = row * 16 + (c16 ^ (row & 7));
        As[d] = gA[f];
        Bs[d] = gB[f];
    }
    __syncthreads();
    const int w = t >> 6, l = t & 63;
    const int wm = (w & 1) * 64, wn = (w >> 1) * 64;
    const int lin = l & 15, kq = l >> 4;
    f32x4 acc[4][4] = {};
#pragma unroll
    for (int s = 0; s < 4; ++s) {
        bf16x8 a[4], b[4];
#pragma unroll
        for (int mi = 0; mi < 4; ++mi) {
            const int row = wm + mi * 16 + lin;
            a[mi] = *(const bf16x8*)&As[row * 16 + ((s * 4 + kq) ^ (row & 7))];
        }
#pragma unroll
        for (int ni = 0; ni < 4; ++ni) {
            const int row = wn + ni * 16 + lin;
            b[ni] = *(const bf16x8*)&Bs[row * 16 + ((s * 4 + kq) ^ (row & 7))];
        }
#pragma unroll
        for (int mi = 0; mi < 4; ++mi)
#pragma unroll
            for (int ni = 0; ni < 4; ++ni)
                acc[mi][ni] = __builtin_amdgcn_mfma_f32_16x16x32_bf16(
                    a[mi], b[ni], acc[mi][ni], 0, 0, 0);
    }
    const int rq = kq * 4;
#pragma unroll
    for (int ni = 0; ni < 4; ++ni) {
        const int col = c0 + wn + ni * 16 + lin;
#pragma unroll
        for (int mi = 0; mi < 4; ++mi) {
            const int row = r0 + wm + mi * 16 + rq;
#pragma unroll
            for (int r = 0; r < 4; ++r)
                HST[(size_t)(row + r) * 256 + col] = f2bf(acc[mi][ni][r]);
        }
    }
}

// ---------- per-target edge reduce -> agg (bf16) ----------
// 2 targets/block; per target 4 edge-slots x 32 lanes; LDS reduce of slot partials.
__launch_bounds__(256)
__global__ void k_edge(const unsigned short* __restrict__ HST, const float* __restrict__ efg,
                       const int* __restrict__ ssrc, const int* __restrict__ rowstart,
                       const float* __restrict__ Wmsg, const float* __restrict__ bmsg,
                       unsigned short* __restrict__ agg_bf) {
    __shared__ float4 part[2][4][32];
    const int t = threadIdx.x;
    const int b = blockIdx.y;
    const int tl = t >> 7;               // target-local index 0..1
    const int tg = blockIdx.x * 2 + tl;
    const int slot = (t >> 5) & 3;
    const int lane = t & 31;
    const int c = lane * 4;
    const float4 w3 = *(const float4*)&Wmsg[256 * 128 + c];
    const float4 bm = *(const float4*)&bmsg[c];
    const size_t base = (size_t)b * kN;
    const us4 htu = *(const us4*)&HST[(base + tg) * 256 + 128 + c];
    const float hb0 = bf2f(htu.x) + bm.x;
    const float hb1 = bf2f(htu.y) + bm.y;
    const float hb2 = bf2f(htu.z) + bm.z;
    const float hb3 = bf2f(htu.w) + bm.w;
    const float* efb = efg + b * kE;
    const int j0 = rowstart[tg], j1 = rowstart[tg + 1];
    float a0 = 0.f, a1 = 0.f, a2 = 0.f, a3 = 0.f;
    for (int j = j0 + slot; j < j1; j += 4) {
        const int s = ssrc[j];
        const float ef = efb[j];
        const us4 hs = *(const us4*)&HST[(base + s) * 256 + c];
        a0 += selu_f(bf2f(hs.x) + fmaf(ef, w3.x, hb0));
        a1 += selu_f(bf2f(hs.y) + fmaf(ef, w3.y, hb1));
        a2 += selu_f(bf2f(hs.z) + fmaf(ef, w3.z, hb2));
        a3 += selu_f(bf2f(hs.w) + fmaf(ef, w3.w, hb3));
    }
    part[tl][slot][lane] = make_float4(a0, a1, a2, a3);
    __syncthreads();
    if (slot == 0) {
        const float4 p1 = part[tl][1][lane];
        const float4 p2 = part[tl][2][lane];
        const float4 p3 = part[tl][3][lane];
        a0 += p1.x + p2.x + p3.x;
        a1 += p1.y + p2.y + p3.y;
        a2 += p1.z + p2.z + p3.z;
        a3 += p1.w + p2.w + p3.w;
        us4 o;
        o.x = f2bf(a0);
        o.y = f2bf(a1);
        o.z = f2bf(a2);
        o.w = f2bf(a3);
        *(us4*)&agg_bf[(base + tg) * 128 + c] = o;
    }
}

// ---------- fused gi-GEMM + gh-GEMM + GRU (+ pooling on last iter) ----------
__launch_bounds__(256)
__global__ void k_gigru(const unsigned short* __restrict__ agg_bf,
                        const unsigned short* __restrict__ h_bf_in,
                        const unsigned short* __restrict__ Wfused,
                        const float* __restrict__ bihP, const float* __restrict__ bhhP,
                        float* __restrict__ h, unsigned short* __restrict__ h_bf_out,
                        float* __restrict__ pooled, int lastIter) {
    __shared__ uint4 As[2048];  // 128 x 128 bf16
    __shared__ uint4 Bs[1536];  // 96 x 128 bf16
    const int t = threadIdx.x;
    const int r0 = blockIdx.x * 128;
    const int y = blockIdx.y;  // [0,4): 96 col' each
    const int w = t >> 6, l = t & 63;
    const int wm = (w & 1) * 64, wc0 = (w >> 1) * 48;
    const int lin = l & 15, kq = l >> 4, rq = kq * 4;
    f32x4 acc[4][3] = {};
    f32x4 accN[4] = {};
#pragma unroll
    for (int stage = 0; stage < 2; ++stage) {
        const unsigned short* Ap = stage ? h_bf_in : agg_bf;
        const uint4* gA = (const uint4*)(Ap + (size_t)r0 * 128);
#pragma unroll
        for (int i = 0; i < 8; ++i) {
            const int f = i * 256 + t;
            const int row = f >> 4, c16 = f & 15;
            As[row * 16 + (c16 ^ (row & 7))] = gA[f];
        }
        const uint4* gW = (const uint4*)Wfused;  // [384][32] chunks
#pragma unroll
        for (int i = 0; i < 6; ++i) {
            const int f = i * 256 + t;  // < 1536
            const int j = f >> 4, c16 = f & 15;
            Bs[j * 16 + (c16 ^ (j & 7))] = gW[(size_t)(y * 96 + j) * 32 + stage * 16 + c16];
        }
        __syncthreads();
#pragma unroll
        for (int ks = 0; ks < 4; ++ks) {
            bf16x8 a[4], b[3];
#pragma unroll
            for (int mi = 0; mi < 4; ++mi) {
                const int row = wm + mi * 16 + lin;
                a[mi] = *(const bf16x8*)&As[row * 16 + ((ks * 4 + kq) ^ (row & 7))];
            }
#pragma unroll
            for (int ni = 0; ni < 3; ++ni) {
                const int row = wc0 + ni * 16 + lin;
                b[ni] = *(const bf16x8*)&Bs[row * 16 + ((ks * 4 + kq) ^ (row & 7))];
            }
#pragma unroll
            for (int mi = 0; mi < 4; ++mi) {
                acc[mi][0] = __builtin_amdgcn_mfma_f32_16x16x32_bf16(a[mi], b[0], acc[mi][0], 0, 0, 0);
                acc[mi][1] = __builtin_amdgcn_mfma_f32_16x16x32_bf16(a[mi], b[1], acc[mi][1], 0, 0, 0);
                if (stage == 0)
                    acc[mi][2] = __builtin_amdgcn_mfma_f32_16x16x32_bf16(a[mi], b[2], acc[mi][2], 0, 0, 0);
                else
                    accN[mi] = __builtin_amdgcn_mfma_f32_16x16x32_bf16(a[mi], b[2], accN[mi], 0, 0, 0);
            }
        }
        __syncthreads();
    }
    // epilogue: GRU (+ optional pooled accumulation)
    const int colR = y * 96 + wc0 + lin;  // col' of r-gate
    const float bR = bihP[colR] + bhhP[colR];
    const float bZ = bihP[colR + 16] + bhhP[colR + 16];
    const float biN = bihP[colR + 32];
    const float bhN = bhhP[colR + 32];
    const int dgg = y * 2 + (wc0 / 48);
    const int d = dgg * 16 + lin;  // h column
    const int bb = r0 >> 10;       // batch of this row-tile
    float psum = 0.f;
#pragma unroll
    for (int mi = 0; mi < 4; ++mi) {
#pragma unroll
        for (int r = 0; r < 4; ++r) {
            const int row = r0 + wm + mi * 16 + rq + r;
            const float rr = sigmoid_f(acc[mi][0][r] + bR);
            const float zz = sigmoid_f(acc[mi][1][r] + bZ);
            const float i_n = acc[mi][2][r] + biN;
            const float h_n = accN[mi][r] + bhN;
            const float nn = tanhf(fmaf(rr, h_n, i_n));
            const size_t idx = (size_t)row * 128 + d;
            const float hv = h[idx];
            const float o = fmaf(zz, hv - nn, nn);
            h[idx] = o;
            h_bf_out[idx] = f2bf(o);
            psum += o;
        }
    }
    if (lastIter) atomicAdd(&pooled[bb * 128 + d], psum);
}

// ---------- head (reads pooled) ----------
__global__ void k_head(const float* __restrict__ pooled,
                       const float* __restrict__ Wr1, const float* __restrict__ br1,
                       const float* __restrict__ Wr2, const float* __restrict__ br2,
                       const float* __restrict__ Wpol, const float* __restrict__ bpol,
                       float* __restrict__ out) {
    __shared__ float p[128], t1[128];
    const int b = blockIdx.x, d = threadIdx.x;
    p[d] = pooled[b * 128 + d];
    __syncthreads();
    float acc = br1[d];
    for (int k = 0; k < 128; ++k) acc = fmaf(p[k], Wr1[k * 128 + d], acc);
    t1[d] = selu_f(acc);
    __syncthreads();
    acc = br2[d];
    for (int k = 0; k < 128; ++k) acc = fmaf(t1[k], Wr2[k * 128 + d], acc);
    __syncthreads();
    p[d] = selu_f(acc);
    __syncthreads();
    if (d < 64) {
        float o = bpol[d];
        for (int k = 0; k < 128; ++k) o = fmaf(p[k], Wpol[k * 64 + d], o);
        out[b * 64 + d] = o;
    }
}

extern "C" void kernel_launch(void* const* d_in, const int* in_sizes, int n_in,
                              void* d_out, int out_size, void* d_ws, size_t ws_size,
                              hipStream_t stream) {
    const float* nodef = (const float*)d_in[0];
    const float* edgef = (const float*)d_in[1];
    const int* src = (const int*)d_in[2];
    const int* tgt = (const int*)d_in[3];
    const float* Wmsg = (const float*)d_in[4];
    const float* bmsg = (const float*)d_in[5];
    const float* Wih = (const float*)d_in[6];
    const float* Whh = (const float*)d_in[7];
    const float* bih = (const float*)d_in[8];
    const float* bhh = (const float*)d_in[9];
    const float* Wr1 = (const float*)d_in[10];
    const float* br1 = (const float*)d_in[11];
    const float* Wr2 = (const float*)d_in[12];
    const float* br2 = (const float*)d_in[13];
    const float* Wpol = (const float*)d_in[14];
    const float* bpol = (const float*)d_in[15];
    float* out = (float*)d_out;

    float* ws = (float*)d_ws;
    float* h = ws;                                      // 2,097,152 f
    float* efg = h + 2097152;                           // 262,144 f
    float* bihP = efg + 262144;                         // 384 f
    float* bhhP = bihP + 384;                           // 384 f
    float* pooled = bhhP + 384;                         // 2,048 f
    unsigned short* HST = (unsigned short*)(pooled + 2048);     // 4,194,304 e
    unsigned short* h_bf = HST + 4194304;               // 2,097,152 e
    unsigned short* agg_bf = h_bf + 2097152;            // 2,097,152 e
    unsigned short* WcatT = agg_bf + 2097152;           // 32,768 e
    unsigned short* Wfused = WcatT + 32768;             // 98,304 e
    int* cnt = (int*)(Wfused + 98304);                  // 1,024
    int* cursor = cnt + 1024;                           // 1,024
    int* rowstart = cursor + 1024;                      // 1,040 (1025 used)
    int* sid = rowstart + 1040;                         // 16,384
    int* ssrc = sid + 16384;                            // 16,384

    hipMemsetAsync(cnt, 0, 1024 * sizeof(int), stream);
    hipMemsetAsync(pooled, 0, 2048 * sizeof(float), stream);
    k_h0<<<(kB * kN * kD) / 256, 256, 0, stream>>>(nodef, h, h_bf);
    k_count<<<kE / 256, 256, 0, stream>>>(tgt, cnt);
    k_scan<<<1, 1024, 0, stream>>>(cnt, cursor, rowstart);
    k_scatter<<<kE / 256, 256, 0, stream>>>(src, tgt, cursor, sid, ssrc);
    k_gather_ef<<<(kB * kE) / 256, 256, 0, stream>>>(edgef, src, tgt, sid, efg);
    k_buildw<<<640, 128, 0, stream>>>(Wmsg, Whh, Wih, bih, bhh, WcatT, Wfused, bihP, bhhP);

    for (int it = 0; it < 3; ++it) {
        // [HS | HT] (bf16) = h @ [W1 | W2]
        k_mm256<<<dim3(128, 2), 256, 0, stream>>>(h_bf, WcatT, HST);
        // per-target selu-reduce over sorted edges -> agg (bf16)
        k_edge<<<dim3(kN / 2, kB), 256, 0, stream>>>(HST, efg, ssrc, rowstart, Wmsg, bmsg, agg_bf);
        // gi/gh in registers -> GRU -> h, h_bf (+pooled on last iter)
        k_gigru<<<dim3(128, 4), 256, 0, stream>>>(agg_bf, h_bf, Wfused, bihP, bhhP, h, h_bf,
                                                  pooled, it == 2 ? 1 : 0);
    }

    k_head<<<kB, 128, 0, stream>>>(pooled, Wr1, br1, Wr2, br2, Wpol, bpol, out);
}

// Round 9
// 299.508 us; speedup vs baseline: 1.2639x; 1.0441x over previous
//
#include <hip/hip_runtime.h>
#include <hip/hip_bf16.h>
#include <math.h>

constexpr int kB = 16;
constexpr int kN = 1024;
constexpr int kD = 128;
constexpr int kE = 16384;

typedef short bf16x8 __attribute__((ext_vector_type(8)));
typedef float f32x4 __attribute__((ext_vector_type(4)));
typedef unsigned short us4 __attribute__((ext_vector_type(4)));

__device__ __forceinline__ float selu_f(float x) {
    const float scale = 1.0507009873554805f;
    const float alpha = 1.6732632423543772f;
    return x > 0.f ? scale * x : scale * alpha * (expf(x) - 1.f);
}

__device__ __forceinline__ float sigmoid_f(float x) {
    return 1.f / (1.f + expf(-x));
}

__device__ __forceinline__ float bf2f(unsigned short u) {
    union { unsigned int i; float f; } x;
    x.i = ((unsigned int)u) << 16;
    return x.f;
}

// round-to-nearest-even f32 -> bf16
__device__ __forceinline__ unsigned short f2bf(float f) {
    union { float f; unsigned int i; } u;
    u.f = f;
    const unsigned int r = u.i + 0x7fffu + ((u.i >> 16) & 1u);
    return (unsigned short)(r >> 16);
}

// ---------- h_bf init + tgt histogram (blocks 0..63) ----------
__global__ void k_h0c(const float* __restrict__ nodef, unsigned short* __restrict__ h_bf,
                      const int* __restrict__ tgt, int* __restrict__ cnt) {
    int gid = blockIdx.x * 256 + threadIdx.x;
    h_bf[gid] = f2bf(nodef[gid]);
    if (gid < kE) atomicAdd(&cnt[tgt[gid]], 1);
}

__global__ void k_scan(const int* __restrict__ cnt, int* __restrict__ cursor,
                       int* __restrict__ rowstart) {
    __shared__ int s[kN];
    int t = threadIdx.x;
    int own = cnt[t];
    s[t] = own;
    __syncthreads();
    for (int off = 1; off < kN; off <<= 1) {
        int add = (t >= off) ? s[t - off] : 0;
        __syncthreads();
        s[t] += add;
        __syncthreads();
    }
    int excl = s[t] - own;
    cursor[t] = excl;
    rowstart[t] = excl;
    if (t == kN - 1) rowstart[kN] = s[t];
}

__global__ void k_scatter(const int* __restrict__ src, const int* __restrict__ tgt,
                          int* __restrict__ cursor, int* __restrict__ sid,
                          int* __restrict__ ssrc) {
    int e = blockIdx.x * 256 + threadIdx.x;
    int tg = tgt[e];
    int pos = atomicAdd(&cursor[tg], 1);
    sid[pos] = e;
    ssrc[pos] = src[e];
}

__global__ void k_gather_ef(const float* __restrict__ edgef, const int* __restrict__ src,
                            const int* __restrict__ tgt, const int* __restrict__ sid,
                            float* __restrict__ efg) {
    int gid = blockIdx.x * 256 + threadIdx.x;  // < kB*kE
    int b = gid >> 14;
    int i = gid & (kE - 1);
    int eid = sid[i];
    efg[gid] = edgef[(size_t)b * kN * kN + (size_t)src[eid] * kN + tgt[eid]];
}

// Weight prep: WcatT (256x128) = [W1^T | W2^T]; Wfused (384x256) gate-interleaved
// col' f = dg*48 + g*16 + di <-> orig col = g*128 + dg*16 + di; k<128: Wih, k>=128: Whh.
__global__ void k_buildw(const float* __restrict__ Wmsg, const float* __restrict__ Whh,
                         const float* __restrict__ Wih,
                         const float* __restrict__ bih, const float* __restrict__ bhh,
                         unsigned short* __restrict__ WcatT,
                         unsigned short* __restrict__ Wfused,
                         float* __restrict__ bihP, float* __restrict__ bhhP) {
    const int j = blockIdx.x;   // 640
    const int k = threadIdx.x;  // 128
    if (j < 256) {
        float v = (j < 128) ? Wmsg[k * 128 + j] : Wmsg[(128 + k) * 128 + (j - 128)];
        WcatT[j * 128 + k] = f2bf(v);
    } else {
        const int f = j - 256;                 // col' in [0,384)
        const int dg = f / 48, rem = f % 48;
        const int g = rem / 16, di = rem % 16;
        const int orig = g * 128 + dg * 16 + di;
        Wfused[(size_t)f * 256 + k] = f2bf(Wih[(size_t)orig * 128 + k]);
        Wfused[(size_t)f * 256 + 128 + k] = f2bf(Whh[(size_t)orig * 128 + k]);
        if (k == 0) {
            bihP[f] = bih[orig];
            bhhP[f] = bhh[orig];
        }
    }
}

// ---------- MFMA GEMM: HST[.][256] = h_bf @ WcatT^T (bf16 out) ----------
__launch_bounds__(256)
__global__ void k_mm256(const unsigned short* __restrict__ A,
                        const unsigned short* __restrict__ Bt,
                        unsigned short* __restrict__ HST) {
    __shared__ uint4 As[2048];
    __shared__ uint4 Bs[2048];
    const int t = threadIdx.x;
    const int r0 = blockIdx.x * 128;
    const int c0 = blockIdx.y * 128;
    const uint4* gA = (const uint4*)(A + (size_t)r0 * 128);
    const uint4* gB = (const uint4*)(Bt + (size_t)c0 * 128);
#pragma unroll
    for (int i = 0; i < 8; ++i) {
        const int f = i * 256 + t;
        const int row = f >> 4, c16 = f & 15;
        const int d = row * 16 + (c16 ^ (row & 7));
        As[d] = gA[f];
        Bs[d] = gB[f];
    }
    __syncthreads();
    const int w = t >> 6, l = t & 63;
    const int wm = (w & 1) * 64, wn = (w >> 1) * 64;
    const int lin = l & 15, kq = l >> 4;
    f32x4 acc[4][4] = {};
#pragma unroll
    for (int s = 0; s < 4; ++s) {
        bf16x8 a[4], b[4];
#pragma unroll
        for (int mi = 0; mi < 4; ++mi) {
            const int row = wm + mi * 16 + lin;
            a[mi] = *(const bf16x8*)&As[row * 16 + ((s * 4 + kq) ^ (row & 7))];
        }
#pragma unroll
        for (int ni = 0; ni < 4; ++ni) {
            const int row = wn + ni * 16 + lin;
            b[ni] = *(const bf16x8*)&Bs[row * 16 + ((s * 4 + kq) ^ (row & 7))];
        }
#pragma unroll
        for (int mi = 0; mi < 4; ++mi)
#pragma unroll
            for (int ni = 0; ni < 4; ++ni)
                acc[mi][ni] = __builtin_amdgcn_mfma_f32_16x16x32_bf16(
                    a[mi], b[ni], acc[mi][ni], 0, 0, 0);
    }
    const int rq = kq * 4;
#pragma unroll
    for (int ni = 0; ni < 4; ++ni) {
        const int col = c0 + wn + ni * 16 + lin;
#pragma unroll
        for (int mi = 0; mi < 4; ++mi) {
            const int row = r0 + wm + mi * 16 + rq;
#pragma unroll
            for (int r = 0; r < 4; ++r)
                HST[(size_t)(row + r) * 256 + col] = f2bf(acc[mi][ni][r]);
        }
    }
}

// ---------- per-target edge reduce -> agg (bf16) ----------
__launch_bounds__(256)
__global__ void k_edge(const unsigned short* __restrict__ HST, const float* __restrict__ efg,
                       const int* __restrict__ ssrc, const int* __restrict__ rowstart,
                       const float* __restrict__ Wmsg, const float* __restrict__ bmsg,
                       unsigned short* __restrict__ agg_bf) {
    __shared__ float4 part[2][4][32];
    const int t = threadIdx.x;
    const int b = blockIdx.y;
    const int tl = t >> 7;               // target-local index 0..1
    const int tg = blockIdx.x * 2 + tl;
    const int slot = (t >> 5) & 3;
    const int lane = t & 31;
    const int c = lane * 4;
    const float4 w3 = *(const float4*)&Wmsg[256 * 128 + c];
    const float4 bm = *(const float4*)&bmsg[c];
    const size_t base = (size_t)b * kN;
    const us4 htu = *(const us4*)&HST[(base + tg) * 256 + 128 + c];
    const float hb0 = bf2f(htu.x) + bm.x;
    const float hb1 = bf2f(htu.y) + bm.y;
    const float hb2 = bf2f(htu.z) + bm.z;
    const float hb3 = bf2f(htu.w) + bm.w;
    const float* efb = efg + b * kE;
    const int j0 = rowstart[tg], j1 = rowstart[tg + 1];
    float a0 = 0.f, a1 = 0.f, a2 = 0.f, a3 = 0.f;
    for (int j = j0 + slot; j < j1; j += 4) {
        const int s = ssrc[j];
        const float ef = efb[j];
        const us4 hs = *(const us4*)&HST[(base + s) * 256 + c];
        a0 += selu_f(bf2f(hs.x) + fmaf(ef, w3.x, hb0));
        a1 += selu_f(bf2f(hs.y) + fmaf(ef, w3.y, hb1));
        a2 += selu_f(bf2f(hs.z) + fmaf(ef, w3.z, hb2));
        a3 += selu_f(bf2f(hs.w) + fmaf(ef, w3.w, hb3));
    }
    part[tl][slot][lane] = make_float4(a0, a1, a2, a3);
    __syncthreads();
    if (slot == 0) {
        const float4 p1 = part[tl][1][lane];
        const float4 p2 = part[tl][2][lane];
        const float4 p3 = part[tl][3][lane];
        a0 += p1.x + p2.x + p3.x;
        a1 += p1.y + p2.y + p3.y;
        a2 += p1.z + p2.z + p3.z;
        a3 += p1.w + p2.w + p3.w;
        us4 o;
        o.x = f2bf(a0);
        o.y = f2bf(a1);
        o.z = f2bf(a2);
        o.w = f2bf(a3);
        *(us4*)&agg_bf[(base + tg) * 128 + c] = o;
    }
}

// ---------- fused gi-GEMM + gh-GEMM + GRU (+ pooling on last iter) ----------
// Ping-pong h: reads h_bf_in (stage-1 A tile), writes h_bf_out (separate buffer).
// hv for the GRU comes from the stage-1 LDS A-tile (no fp32 h buffer at all).
__launch_bounds__(256)
__global__ void k_gigru(const unsigned short* __restrict__ agg_bf,
                        const unsigned short* __restrict__ h_bf_in,
                        const unsigned short* __restrict__ Wfused,
                        const float* __restrict__ bihP, const float* __restrict__ bhhP,
                        unsigned short* __restrict__ h_bf_out,
                        float* __restrict__ pooled, int lastIter) {
    __shared__ uint4 As[2048];  // 128 x 128 bf16
    __shared__ uint4 Bs[1536];  // 96 x 128 bf16
    const int t = threadIdx.x;
    const int r0 = blockIdx.x * 128;
    const int y = blockIdx.y;  // [0,4): 96 col' each
    const int w = t >> 6, l = t & 63;
    const int wm = (w & 1) * 64, wc0 = (w >> 1) * 48;
    const int lin = l & 15, kq = l >> 4, rq = kq * 4;
    f32x4 acc[4][3] = {};
    f32x4 accN[4] = {};
#pragma unroll
    for (int stage = 0; stage < 2; ++stage) {
        const unsigned short* Ap = stage ? h_bf_in : agg_bf;
        const uint4* gA = (const uint4*)(Ap + (size_t)r0 * 128);
#pragma unroll
        for (int i = 0; i < 8; ++i) {
            const int f = i * 256 + t;
            const int row = f >> 4, c16 = f & 15;
            As[row * 16 + (c16 ^ (row & 7))] = gA[f];
        }
        const uint4* gW = (const uint4*)Wfused;  // [384][32] chunks
#pragma unroll
        for (int i = 0; i < 6; ++i) {
            const int f = i * 256 + t;  // < 1536
            const int j = f >> 4, c16 = f & 15;
            Bs[j * 16 + (c16 ^ (j & 7))] = gW[(size_t)(y * 96 + j) * 32 + stage * 16 + c16];
        }
        __syncthreads();
#pragma unroll
        for (int ks = 0; ks < 4; ++ks) {
            bf16x8 a[4], b[3];
#pragma unroll
            for (int mi = 0; mi < 4; ++mi) {
                const int row = wm + mi * 16 + lin;
                a[mi] = *(const bf16x8*)&As[row * 16 + ((ks * 4 + kq) ^ (row & 7))];
            }
#pragma unroll
            for (int ni = 0; ni < 3; ++ni) {
                const int row = wc0 + ni * 16 + lin;
                b[ni] = *(const bf16x8*)&Bs[row * 16 + ((ks * 4 + kq) ^ (row & 7))];
            }
#pragma unroll
            for (int mi = 0; mi < 4; ++mi) {
                acc[mi][0] = __builtin_amdgcn_mfma_f32_16x16x32_bf16(a[mi], b[0], acc[mi][0], 0, 0, 0);
                acc[mi][1] = __builtin_amdgcn_mfma_f32_16x16x32_bf16(a[mi], b[1], acc[mi][1], 0, 0, 0);
                if (stage == 0)
                    acc[mi][2] = __builtin_amdgcn_mfma_f32_16x16x32_bf16(a[mi], b[2], acc[mi][2], 0, 0, 0);
                else
                    accN[mi] = __builtin_amdgcn_mfma_f32_16x16x32_bf16(a[mi], b[2], accN[mi], 0, 0, 0);
            }
        }
        __syncthreads();
    }
    // epilogue: GRU; hv read from stage-1 LDS A-tile (h_bf rows of this block)
    const int colR = y * 96 + wc0 + lin;  // col' of r-gate
    const float bR = bihP[colR] + bhhP[colR];
    const float bZ = bihP[colR + 16] + bhhP[colR + 16];
    const float biN = bihP[colR + 32];
    const float bhN = bhhP[colR + 32];
    const int dgg = y * 2 + (wc0 / 48);
    const int d = dgg * 16 + lin;  // h column
    const int bb = r0 >> 10;       // batch of this row-tile
    const int dc = d >> 3, de = d & 7;
    float psum = 0.f;
#pragma unroll
    for (int mi = 0; mi < 4; ++mi) {
#pragma unroll
        for (int r = 0; r < 4; ++r) {
            const int rowL = wm + mi * 16 + rq + r;
            const float rr = sigmoid_f(acc[mi][0][r] + bR);
            const float zz = sigmoid_f(acc[mi][1][r] + bZ);
            const float i_n = acc[mi][2][r] + biN;
            const float h_n = accN[mi][r] + bhN;
            const float nn = tanhf(fmaf(rr, h_n, i_n));
            const float hv = bf2f(((const unsigned short*)&As[rowL * 16 + (dc ^ (rowL & 7))])[de]);
            const float o = fmaf(zz, hv - nn, nn);
            h_bf_out[(size_t)(r0 + rowL) * 128 + d] = f2bf(o);
            psum += o;
        }
    }
    if (lastIter) atomicAdd(&pooled[bb * 128 + d], psum);
}

// ---------- head (reads pooled) ----------
__global__ void k_head(const float* __restrict__ pooled,
                       const float* __restrict__ Wr1, const float* __restrict__ br1,
                       const float* __restrict__ Wr2, const float* __restrict__ br2,
                       const float* __restrict__ Wpol, const float* __restrict__ bpol,
                       float* __restrict__ out) {
    __shared__ float p[128], t1[128];
    const int b = blockIdx.x, d = threadIdx.x;
    p[d] = pooled[b * 128 + d];
    __syncthreads();
    float acc = br1[d];
    for (int k = 0; k < 128; ++k) acc = fmaf(p[k], Wr1[k * 128 + d], acc);
    t1[d] = selu_f(acc);
    __syncthreads();
    acc = br2[d];
    for (int k = 0; k < 128; ++k) acc = fmaf(t1[k], Wr2[k * 128 + d], acc);
    __syncthreads();
    p[d] = selu_f(acc);
    __syncthreads();
    if (d < 64) {
        float o = bpol[d];
        for (int k = 0; k < 128; ++k) o = fmaf(p[k], Wpol[k * 64 + d], o);
        out[b * 64 + d] = o;
    }
}

extern "C" void kernel_launch(void* const* d_in, const int* in_sizes, int n_in,
                              void* d_out, int out_size, void* d_ws, size_t ws_size,
                              hipStream_t stream) {
    const float* nodef = (const float*)d_in[0];
    const float* edgef = (const float*)d_in[1];
    const int* src = (const int*)d_in[2];
    const int* tgt = (const int*)d_in[3];
    const float* Wmsg = (const float*)d_in[4];
    const float* bmsg = (const float*)d_in[5];
    const float* Wih = (const float*)d_in[6];
    const float* Whh = (const float*)d_in[7];
    const float* bih = (const float*)d_in[8];
    const float* bhh = (const float*)d_in[9];
    const float* Wr1 = (const float*)d_in[10];
    const float* br1 = (const float*)d_in[11];
    const float* Wr2 = (const float*)d_in[12];
    const float* br2 = (const float*)d_in[13];
    const float* Wpol = (const float*)d_in[14];
    const float* bpol = (const float*)d_in[15];
    float* out = (float*)d_out;

    float* ws = (float*)d_ws;
    float* efg = ws;                                    // 262,144 f
    float* bihP = efg + 262144;                         // 384 f
    float* bhhP = bihP + 384;                           // 384 f
    int* cnt = (int*)(bhhP + 384);                      // 1,024 i   (zeroed together)
    float* pooled = (float*)(cnt + 1024);               // 2,048 f   (zeroed together)
    unsigned short* HST = (unsigned short*)(pooled + 2048);     // 4,194,304 e
    unsigned short* hbfA = HST + 4194304;               // 2,097,152 e
    unsigned short* hbfB = hbfA + 2097152;              // 2,097,152 e
    unsigned short* agg_bf = hbfB + 2097152;            // 2,097,152 e
    unsigned short* WcatT = agg_bf + 2097152;           // 32,768 e
    unsigned short* Wfused = WcatT + 32768;             // 98,304 e
    int* cursor = (int*)(Wfused + 98304);               // 1,024
    int* rowstart = cursor + 1024;                      // 1,040 (1025 used)
    int* sid = rowstart + 1040;                         // 16,384
    int* ssrc = sid + 16384;                            // 16,384

    hipMemsetAsync(cnt, 0, (1024 + 2048) * sizeof(int), stream);
    k_h0c<<<(kB * kN * kD) / 256, 256, 0, stream>>>(nodef, hbfA, tgt, cnt);
    k_scan<<<1, 1024, 0, stream>>>(cnt, cursor, rowstart);
    k_scatter<<<kE / 256, 256, 0, stream>>>(src, tgt, cursor, sid, ssrc);
    k_gather_ef<<<(kB * kE) / 256, 256, 0, stream>>>(edgef, src, tgt, sid, efg);
    k_buildw<<<640, 128, 0, stream>>>(Wmsg, Whh, Wih, bih, bhh, WcatT, Wfused, bihP, bhhP);

    for (int it = 0; it < 3; ++it) {
        unsigned short* hcur = (it & 1) ? hbfB : hbfA;
        unsigned short* hnxt = (it & 1) ? hbfA : hbfB;
        // [HS | HT] (bf16) = h @ [W1 | W2]
        k_mm256<<<dim3(128, 2), 256, 0, stream>>>(hcur, WcatT, HST);
        // per-target selu-reduce over sorted edges -> agg (bf16)
        k_edge<<<dim3(kN / 2, kB), 256, 0, stream>>>(HST, efg, ssrc, rowstart, Wmsg, bmsg, agg_bf);
        // gi/gh in registers -> GRU -> h_bf (ping-pong) (+pooled on last iter)
        k_gigru<<<dim3(128, 4), 256, 0, stream>>>(agg_bf, hcur, Wfused, bihP, bhhP, hnxt,
                                                  pooled, it == 2 ? 1 : 0);
    }

    k_head<<<kB, 128, 0, stream>>>(pooled, Wr1, br1, Wr2, br2, Wpol, bpol, out);
}